// Round 8
// baseline (577.352 us; speedup 1.0000x reference)
//
#include <hip/hip_runtime.h>

// SparseResidualBlock on MI355X (gfx950).
// Round 10: delete the bn_relu pass by fusing BN1+ReLU into conv2's A-staging.
//  - conv1: EXACT R4 conv (verified 3x: ~119us, VGPR 88, no spill).
//  - conv2 (conv_bn_kernel): A-gather reads PRE-BN fp16 tmp; BN+ReLU applied
//    in-register at stage time. Lane's channel segment sigma = sg^rs is
//    per-lane CONSTANT -> 8 channels per ch-half -> BN consts = 32 named VGPRs.
//    Schedule per chunk (single barrier, R4 hazard structure):
//      {Aload(c+1)->u0..u3 ; Bstage(c+1) gload_lds ; compute(c) ;
//       vmcnt(0) ; bnpack+ds_write A(c+1) ; lgkmcnt(0) ; s_barrier}
//    id<0 neighbors -> post-BN ZEROS (relu(bs)!=0, select on output).
//  - Register discipline: only NAMED non-array values held across compute
//    (u0..u3=16, BN=32, idx=36, acc=64 ~ 165 < 256 cap at 2 waves/SIMD).
//    R5/R8 spills came from cross-iteration ARRAYS via lambda params.
//  - ph plane recycled as conv2 output (tmp is gathered, can't overwrite).
// Tripwires next round: conv_bn WRITE_SIZE ~77MB / VGPR < 200 (else spill),
// SQ_LDS_BANK_CONFLICT ~ 0 (ds_write_b128 is contiguous-1KB, canonical).

#define N_ACT 300000
#define NTAP  9
#define EPSV  1e-4f
#define GSB   2048          // grid-stride blocks for streaming kernels
#define NWU   4800000       // 38.4M elems / 8 per thread

using f16x8 = __attribute__((ext_vector_type(8))) _Float16;
using f32x4 = __attribute__((ext_vector_type(4))) float;

// ---- workspace layout (bytes) ----
#define OFF_PH    0UL                     // 76,800,000 : fp16 plane (x-half, then conv2 out)
#define OFF_TMP   76800000UL              // 76,800,000 : fp16 conv1 output (pre-BN)
#define OFF_W1    230400000UL             // 294,912 : 9 taps x 2 chunks x 128 n x 64 k fp16
#define OFF_W2    (OFF_W1 + 294912UL)
#define OFF_STATS (OFF_W2 + 294912UL)     // 512 floats: sum1, sq1, sum2, sq2
#define OFF_ZBUF  (OFF_STATS + 2048UL)    // 256 B zeros (gather target for idx<0, conv1)

__device__ __forceinline__ unsigned short f2h(float v) {
  _Float16 h = (_Float16)v;               // RNE
  return __builtin_bit_cast(unsigned short, h);
}

// ---- fused: x -> fp16 plane (grid-stride) + weight prep + stats zeroing ----
__global__ void tohalf_prep_kernel(const float* __restrict__ x, unsigned short* __restrict__ ph,
                                   const float* __restrict__ W1, const float* __restrict__ W2,
                                   unsigned short* __restrict__ w1, unsigned short* __restrict__ w2,
                                   float* __restrict__ zstats) {
  int pb = blockIdx.x - GSB;
  if (pb >= 0) {                          // ---- prep part ----
    int t = threadIdx.x;
    if (pb == 36) {                       // stats (512 f) + zbuf (64 f) zeroing
      for (int i = t; i < 576; i += 256) zstats[i] = 0.f;
      return;
    }
    int w = pb / 18, rem = pb % 18;
    int tap = rem >> 1, ch = rem & 1;
    const float* W = w ? W2 : W1;
    unsigned short* o = w ? w2 : w1;
    int n  = t >> 1;
    int s0 = (t & 1) * 4;
    for (int s = s0; s < s0 + 4; ++s) {
      int sigma = s ^ (n & 7);
      for (int j = 0; j < 8; ++j) {
        int   k = ch * 64 + sigma * 8 + j;
        float v = W[tap * 16384 + k * 128 + n];
        o[rem * 8192 + n * 64 + s * 8 + j] = f2h(v);
      }
    }
    return;
  }
  for (long u = blockIdx.x * 256 + threadIdx.x; u < NWU; u += (long)GSB * 256) {
    long i = u * 8;
    float4 a = *(const float4*)(x + i);
    float4 b = *(const float4*)(x + i + 4);
    uint4 p;
    p.x = (unsigned)f2h(a.x) | ((unsigned)f2h(a.y) << 16);
    p.y = (unsigned)f2h(a.z) | ((unsigned)f2h(a.w) << 16);
    p.z = (unsigned)f2h(b.x) | ((unsigned)f2h(b.y) << 16);
    p.w = (unsigned)f2h(b.z) | ((unsigned)f2h(b.w) << 16);
    *(uint4*)(ph + i) = p;
  }
}

// ---- conv1: EXACT R4 kernel (A gather + B via global_load_lds, 2-phase) ----
__global__ __launch_bounds__(256, 2)
void conv_kernel(const unsigned short* __restrict__ pH, const int* __restrict__ nbr,
                 const unsigned short* __restrict__ wH,
                 unsigned short* __restrict__ outp, float* __restrict__ ssum, float* __restrict__ ssq,
                 const unsigned short* __restrict__ zbuf) {
  __shared__ char smem[65536];
  const int t  = threadIdx.x;
  const int wv = t >> 6, ln = t & 63;
  const int m0 = blockIdx.x * 128;
  const int rs = ln >> 3, sg = ln & 7;
  const int lane16 = ln & 15, g = ln >> 4;

  int idx[NTAP][4];
#pragma unroll
  for (int tap = 0; tap < NTAP; ++tap)
#pragma unroll
    for (int it = 0; it < 4; ++it) {
      int gm = m0 + wv * 32 + it * 8 + rs;
      idx[tap][it] = (gm < N_ACT) ? nbr[gm * 9 + tap] : -1;
    }

  f32x4 acc[16];
#pragma unroll
  for (int i = 0; i < 16; ++i) acc[i] = f32x4{0.f, 0.f, 0.f, 0.f};

  auto stage = [&](int c, int p) {
    const int tap = c >> 1, ch = c & 1;
#pragma unroll
    for (int it = 0; it < 4; ++it) {
      int r     = wv * 32 + it * 8 + rs;
      int sigma = sg ^ (r & 7);
      int id    = idx[tap][it];
      long off  = (long)(id >= 0 ? id : 0) * 128 + ch * 64 + sigma * 8;
      const unsigned short* gs = (id >= 0) ? (pH + off) : (zbuf + sigma * 8);
      int lo = p * 16384 + r * 128 + sg * 16;
      __builtin_amdgcn_global_load_lds((const __attribute__((address_space(1))) void*)gs,
                                       (__attribute__((address_space(3))) void*)(smem + lo), 16, 0, 0);
    }
    const char* gb = (const char*)wH + (tap * 2 + ch) * 16384;
#pragma unroll
    for (int it = 0; it < 4; ++it) {
      int o = wv * 4096 + it * 1024 + ln * 16;
      __builtin_amdgcn_global_load_lds((const __attribute__((address_space(1))) void*)(gb + o),
                                       (__attribute__((address_space(3))) void*)(smem + 32768 + p * 16384 + o), 16, 0, 0);
    }
  };

  auto compute = [&](int p) {
    const char* bufA = smem + p * 16384;
    const char* bufB = smem + 32768 + p * 16384;
#pragma unroll
    for (int ks = 0; ks < 2; ++ks) {
      f16x8 ah[4], bh[4];
      int sigma = ks * 4 + g;
#pragma unroll
      for (int mt = 0; mt < 4; ++mt) {
        int m = (wv & 1) * 64 + mt * 16 + lane16;
        ah[mt] = *(const f16x8*)(bufA + m * 128 + ((sigma ^ (m & 7)) * 16));
      }
#pragma unroll
      for (int nt = 0; nt < 4; ++nt) {
        int n = (wv >> 1) * 64 + nt * 16 + lane16;
        bh[nt] = *(const f16x8*)(bufB + n * 128 + ((sigma ^ (n & 7)) * 16));
      }
#pragma unroll
      for (int mt = 0; mt < 4; ++mt)
#pragma unroll
        for (int nt = 0; nt < 4; ++nt)
          acc[mt * 4 + nt] = __builtin_amdgcn_mfma_f32_16x16x32_f16(ah[mt], bh[nt], acc[mt * 4 + nt], 0, 0, 0);
    }
  };

  stage(0, 0);
  asm volatile("s_waitcnt vmcnt(0)" ::: "memory");
  __builtin_amdgcn_sched_barrier(0);
  __builtin_amdgcn_s_barrier();

#pragma unroll
  for (int c = 0; c < 17; ++c) {
    stage(c + 1, (c + 1) & 1);
    compute(c & 1);
    asm volatile("s_waitcnt vmcnt(0)" ::: "memory");
    __builtin_amdgcn_sched_barrier(0);
    __builtin_amdgcn_s_barrier();
  }
  compute(1);

  int rowbase = m0 + (wv & 1) * 64;
  int colbase = (wv >> 1) * 64;
  float s[4], q[4];
#pragma unroll
  for (int nt = 0; nt < 4; ++nt) { s[nt] = 0.f; q[nt] = 0.f; }
#pragma unroll
  for (int mt = 0; mt < 4; ++mt)
#pragma unroll
    for (int nt = 0; nt < 4; ++nt)
#pragma unroll
      for (int r = 0; r < 4; ++r) {
        float v  = acc[mt * 4 + nt][r];
        int  row = rowbase + mt * 16 + g * 4 + r;
        int  col = colbase + nt * 16 + lane16;
        if (row < N_ACT) outp[row * 128 + col] = f2h(v);
        s[nt] += v; q[nt] += v * v;
      }
  __syncthreads();
  float* sbuf = (float*)smem;
  float* qbuf = ((float*)smem) + 256;
#pragma unroll
  for (int nt = 0; nt < 4; ++nt) {
    float sv = s[nt], qv = q[nt];
    sv += __shfl_xor(sv, 16, 64); sv += __shfl_xor(sv, 32, 64);
    qv += __shfl_xor(qv, 16, 64); qv += __shfl_xor(qv, 32, 64);
    if (ln < 16) { sbuf[wv * 64 + nt * 16 + ln] = sv; qbuf[wv * 64 + nt * 16 + ln] = qv; }
  }
  __syncthreads();
  if (t < 128) {
    int c = t;
    float tot = (c < 64) ? (sbuf[c] + sbuf[64 + c]) : (sbuf[128 + (c - 64)] + sbuf[192 + (c - 64)]);
    atomicAdd(ssum + c, tot);
  } else {
    int c = t - 128;
    float tot = (c < 64) ? (qbuf[c] + qbuf[64 + c]) : (qbuf[128 + (c - 64)] + qbuf[192 + (c - 64)]);
    atomicAdd(ssq + c, tot);
  }
}

// ---- conv2 with fused BN1+ReLU on the gathered operand ----
__global__ __launch_bounds__(256, 2)
void conv_bn_kernel(const unsigned short* __restrict__ pT, const int* __restrict__ nbr,
                    const unsigned short* __restrict__ wH,
                    const float* __restrict__ s1sum, const float* __restrict__ s1sq,
                    const float* __restrict__ g1, const float* __restrict__ b1,
                    unsigned short* __restrict__ outp,
                    float* __restrict__ ssum, float* __restrict__ ssq) {
  __shared__ char smem[65536];
  const int t  = threadIdx.x;
  const int wv = t >> 6, ln = t & 63;
  const int m0 = blockIdx.x * 128;
  const int rs = ln >> 3, sg = ln & 7;
  const int lane16 = ln & 15, g = ln >> 4;
  const int sig8 = (sg ^ rs) * 8;         // lane-constant channel segment

  int idx[NTAP][4];
#pragma unroll
  for (int tap = 0; tap < NTAP; ++tap)
#pragma unroll
    for (int it = 0; it < 4; ++it) {
      int gm = m0 + wv * 32 + it * 8 + rs;
      idx[tap][it] = (gm < N_ACT) ? nbr[gm * 9 + tap] : -1;
    }

  // BN consts for this lane's 16 channels (ch=0: E, ch=1: O) — named f32x4s
  f32x4 scE0, scE1, bsE0, bsE1, scO0, scO1, bsO0, bsO1;
  {
    auto mk = [&](int base, f32x4& sc0, f32x4& sc1, f32x4& bs0, f32x4& bs1) {
      float4 s0 = *(const float4*)(s1sum + base), s1v = *(const float4*)(s1sum + base + 4);
      float4 q0 = *(const float4*)(s1sq  + base), q1v = *(const float4*)(s1sq  + base + 4);
      float4 g0 = *(const float4*)(g1 + base),    g1v = *(const float4*)(g1 + base + 4);
      float4 e0 = *(const float4*)(b1 + base),    e1v = *(const float4*)(b1 + base + 4);
#pragma unroll
      for (int j = 0; j < 4; ++j) {
        float m = ((const float*)&s0)[j] * (1.f / N_ACT);
        float v = ((const float*)&q0)[j] * (1.f / N_ACT) - m * m;
        float k = rsqrtf(v + EPSV) * ((const float*)&g0)[j];
        sc0[j] = k; bs0[j] = ((const float*)&e0)[j] - m * k;
        m = ((const float*)&s1v)[j] * (1.f / N_ACT);
        v = ((const float*)&q1v)[j] * (1.f / N_ACT) - m * m;
        k = rsqrtf(v + EPSV) * ((const float*)&g1v)[j];
        sc1[j] = k; bs1[j] = ((const float*)&e1v)[j] - m * k;
      }
    };
    mk(sig8, scE0, scE1, bsE0, bsE1);        // ch = 0
    mk(64 + sig8, scO0, scO1, bsO0, bsO1);   // ch = 1
  }

  f32x4 acc[16];
#pragma unroll
  for (int i = 0; i < 16; ++i) acc[i] = f32x4{0.f, 0.f, 0.f, 0.f};

  auto stageB = [&](int c, int p) {
    const char* gb = (const char*)wH + c * 16384;
#pragma unroll
    for (int it = 0; it < 4; ++it) {
      int o = wv * 4096 + it * 1024 + ln * 16;
      __builtin_amdgcn_global_load_lds((const __attribute__((address_space(1))) void*)(gb + o),
                                       (__attribute__((address_space(3))) void*)(smem + 32768 + p * 16384 + o), 16, 0, 0);
    }
  };

  auto compute = [&](int p) {
    const char* bufA = smem + p * 16384;
    const char* bufB = smem + 32768 + p * 16384;
#pragma unroll
    for (int ks = 0; ks < 2; ++ks) {
      f16x8 ah[4], bh[4];
      int sigma = ks * 4 + g;
#pragma unroll
      for (int mt = 0; mt < 4; ++mt) {
        int m = (wv & 1) * 64 + mt * 16 + lane16;
        ah[mt] = *(const f16x8*)(bufA + m * 128 + ((sigma ^ (m & 7)) * 16));
      }
#pragma unroll
      for (int nt = 0; nt < 4; ++nt) {
        int n = (wv >> 1) * 64 + nt * 16 + lane16;
        bh[nt] = *(const f16x8*)(bufB + n * 128 + ((sigma ^ (n & 7)) * 16));
      }
#pragma unroll
      for (int mt = 0; mt < 4; ++mt)
#pragma unroll
        for (int nt = 0; nt < 4; ++nt)
          acc[mt * 4 + nt] = __builtin_amdgcn_mfma_f32_16x16x32_f16(ah[mt], bh[nt], acc[mt * 4 + nt], 0, 0, 0);
    }
  };

  // bn+relu+pack one uint4 (8 halves); E/O chosen by literal ch
  auto cvh = [&](unsigned hb, float sc_, float bs_) -> unsigned {
    float f = (float)__builtin_bit_cast(_Float16, (unsigned short)(hb & 0xffff));
    return (unsigned)f2h(fmaxf(f * sc_ + bs_, 0.f));
  };
  auto bnpk = [&](uint4 u, const f32x4& s0, const f32x4& s1, const f32x4& b0, const f32x4& b1v) -> uint4 {
    uint4 o;
    o.x = cvh(u.x, s0[0], b0[0]) | (cvh(u.x >> 16, s0[1], b0[1]) << 16);
    o.y = cvh(u.y, s0[2], b0[2]) | (cvh(u.y >> 16, s0[3], b0[3]) << 16);
    o.z = cvh(u.z, s1[0], b1v[0]) | (cvh(u.z >> 16, s1[1], b1v[1]) << 16);
    o.w = cvh(u.w, s1[2], b1v[2]) | (cvh(u.w >> 16, s1[3], b1v[3]) << 16);
    return o;
  };

  uint4 u0, u1, u2, u3;                   // named A-staging regs (16 VGPR)
  int   j0, j1, j2, j3;

#define ALOAD(cc)                                                              \
  { const int tap_ = (cc) >> 1, ch_ = (cc) & 1;                                \
    j0 = idx[tap_][0]; j1 = idx[tap_][1]; j2 = idx[tap_][2]; j3 = idx[tap_][3];\
    const unsigned short* bp = pT + ch_ * 64 + sig8;                           \
    u0 = *(const uint4*)(bp + (long)(j0 < 0 ? 0 : j0) * 128);                  \
    u1 = *(const uint4*)(bp + (long)(j1 < 0 ? 0 : j1) * 128);                  \
    u2 = *(const uint4*)(bp + (long)(j2 < 0 ? 0 : j2) * 128);                  \
    u3 = *(const uint4*)(bp + (long)(j3 < 0 ? 0 : j3) * 128); }

#define AWRITE(cc, pp)                                                         \
  { const int ch_ = (cc) & 1;                                                  \
    const f32x4& S0 = ch_ ? scO0 : scE0; const f32x4& S1 = ch_ ? scO1 : scE1;  \
    const f32x4& B0 = ch_ ? bsO0 : bsE0; const f32x4& B1 = ch_ ? bsO1 : bsE1;  \
    uint4 o0 = bnpk(u0, S0, S1, B0, B1), o1 = bnpk(u1, S0, S1, B0, B1);        \
    uint4 o2 = bnpk(u2, S0, S1, B0, B1), o3 = bnpk(u3, S0, S1, B0, B1);        \
    if (j0 < 0) o0 = uint4{0, 0, 0, 0};                                        \
    if (j1 < 0) o1 = uint4{0, 0, 0, 0};                                        \
    if (j2 < 0) o2 = uint4{0, 0, 0, 0};                                        \
    if (j3 < 0) o3 = uint4{0, 0, 0, 0};                                        \
    char* ab = smem + (pp) * 16384 + (wv * 32 + rs) * 128 + sg * 16;           \
    *(uint4*)(ab)        = o0;                                                 \
    *(uint4*)(ab + 1024) = o1;                                                 \
    *(uint4*)(ab + 2048) = o2;                                                 \
    *(uint4*)(ab + 3072) = o3; }

  // prologue: chunk 0 -> parity 0
  ALOAD(0);
  stageB(0, 0);
  asm volatile("s_waitcnt vmcnt(0)" ::: "memory");
  __builtin_amdgcn_sched_barrier(0);
  AWRITE(0, 0);
  asm volatile("s_waitcnt lgkmcnt(0)" ::: "memory");
  __builtin_amdgcn_sched_barrier(0);
  __builtin_amdgcn_s_barrier();

#pragma unroll
  for (int c = 0; c < 17; ++c) {
    ALOAD(c + 1);                         // issue early: hidden under compute
    stageB(c + 1, (c + 1) & 1);
    __builtin_amdgcn_sched_barrier(0);    // pin load issue before MFMA region
    compute(c & 1);
    asm volatile("s_waitcnt vmcnt(0)" ::: "memory");
    __builtin_amdgcn_sched_barrier(0);
    AWRITE(c + 1, (c + 1) & 1);
    asm volatile("s_waitcnt lgkmcnt(0)" ::: "memory");
    __builtin_amdgcn_sched_barrier(0);
    __builtin_amdgcn_s_barrier();
  }
  compute(1);

  // epilogue: fp16 store + BN2 stats
  int rowbase = m0 + (wv & 1) * 64;
  int colbase = (wv >> 1) * 64;
  float s[4], q[4];
#pragma unroll
  for (int nt = 0; nt < 4; ++nt) { s[nt] = 0.f; q[nt] = 0.f; }
#pragma unroll
  for (int mt = 0; mt < 4; ++mt)
#pragma unroll
    for (int nt = 0; nt < 4; ++nt)
#pragma unroll
      for (int r = 0; r < 4; ++r) {
        float v  = acc[mt * 4 + nt][r];
        int  row = rowbase + mt * 16 + g * 4 + r;
        int  col = colbase + nt * 16 + lane16;
        if (row < N_ACT) outp[row * 128 + col] = f2h(v);
        s[nt] += v; q[nt] += v * v;
      }
  __syncthreads();
  float* sbuf = (float*)smem;
  float* qbuf = ((float*)smem) + 256;
#pragma unroll
  for (int nt = 0; nt < 4; ++nt) {
    float sv = s[nt], qv = q[nt];
    sv += __shfl_xor(sv, 16, 64); sv += __shfl_xor(sv, 32, 64);
    qv += __shfl_xor(qv, 16, 64); qv += __shfl_xor(qv, 32, 64);
    if (ln < 16) { sbuf[wv * 64 + nt * 16 + ln] = sv; qbuf[wv * 64 + nt * 16 + ln] = qv; }
  }
  __syncthreads();
  if (t < 128) {
    int c = t;
    float tot = (c < 64) ? (sbuf[c] + sbuf[64 + c]) : (sbuf[128 + (c - 64)] + sbuf[192 + (c - 64)]);
    atomicAdd(ssum + c, tot);
  } else {
    int c = t - 128;
    float tot = (c < 64) ? (qbuf[c] + qbuf[64 + c]) : (qbuf[128 + (c - 64)] + qbuf[192 + (c - 64)]);
    atomicAdd(ssq + c, tot);
  }
#undef ALOAD
#undef AWRITE
}

// ---- BN2 + residual + ReLU (grid-stride; folded stats hoisted) ----
__global__ void final_kernel(const unsigned short* __restrict__ tmp,
                             const float* __restrict__ ssum, const float* __restrict__ ssq,
                             const float* __restrict__ gamma, const float* __restrict__ beta,
                             const float* __restrict__ x, float* __restrict__ outp) {
  long u0 = blockIdx.x * 256 + threadIdx.x;
  int  c  = (int)((u0 * 8) & 127);
  float sc[8], bs[8];
#pragma unroll
  for (int j = 0; j < 8; ++j) {
    float mean = ssum[c + j] * (1.f / N_ACT);
    float var  = ssq[c + j] * (1.f / N_ACT) - mean * mean;
    float k    = rsqrtf(var + EPSV) * gamma[c + j];
    sc[j] = k; bs[j] = beta[c + j] - mean * k;
  }
  for (long u = u0; u < NWU; u += (long)GSB * 256) {
    long i = u * 8;
    f16x8 v = *(const f16x8*)(tmp + i);
    float4 x0 = *(const float4*)(x + i);
    float4 x1 = *(const float4*)(x + i + 4);
    float4 o0, o1;
    o0.x = fmaxf((float)v[0] * sc[0] + bs[0] + x0.x, 0.f);
    o0.y = fmaxf((float)v[1] * sc[1] + bs[1] + x0.y, 0.f);
    o0.z = fmaxf((float)v[2] * sc[2] + bs[2] + x0.z, 0.f);
    o0.w = fmaxf((float)v[3] * sc[3] + bs[3] + x0.w, 0.f);
    o1.x = fmaxf((float)v[4] * sc[4] + bs[4] + x1.x, 0.f);
    o1.y = fmaxf((float)v[5] * sc[5] + bs[5] + x1.y, 0.f);
    o1.z = fmaxf((float)v[6] * sc[6] + bs[6] + x1.z, 0.f);
    o1.w = fmaxf((float)v[7] * sc[7] + bs[7] + x1.w, 0.f);
    *(float4*)(outp + i) = o0;
    *(float4*)(outp + i + 4) = o1;
  }
}

extern "C" void kernel_launch(void* const* d_in, const int* in_sizes, int n_in,
                              void* d_out, int out_size, void* d_ws, size_t ws_size,
                              hipStream_t stream) {
  const float* x   = (const float*)d_in[0];
  const int*   nbr = (const int*)d_in[1];
  const float* W1  = (const float*)d_in[2];
  const float* g1  = (const float*)d_in[3];
  const float* b1  = (const float*)d_in[4];
  const float* W2  = (const float*)d_in[5];
  const float* g2  = (const float*)d_in[6];
  const float* b2  = (const float*)d_in[7];
  float* out = (float*)d_out;
  char*  ws  = (char*)d_ws;

  unsigned short* ph  = (unsigned short*)(ws + OFF_PH);
  unsigned short* tmp = (unsigned short*)(ws + OFF_TMP);
  unsigned short* w1  = (unsigned short*)(ws + OFF_W1);
  unsigned short* w2  = (unsigned short*)(ws + OFF_W2);
  float*          st  = (float*)(ws + OFF_STATS);
  unsigned short* zb  = (unsigned short*)(ws + OFF_ZBUF);

  tohalf_prep_kernel<<<GSB + 37, 256, 0, stream>>>(x, ph, W1, W2, w1, w2, st);
  conv_kernel<<<2344, 256, 0, stream>>>(ph, nbr, w1, tmp, st, st + 128, zb);
  conv_bn_kernel<<<2344, 256, 0, stream>>>(tmp, nbr, w2, st, st + 128, g1, b1, ph, st + 256, st + 384);
  final_kernel<<<GSB, 256, 0, stream>>>(ph, st + 256, st + 384, g2, b2, x, out);
}